// Round 6
// baseline (6128.697 us; speedup 1.0000x reference)
//
#include <hip/hip_runtime.h>

#define T_STEPS 8192
#define BATCH   128
#define HID     96

typedef __fp16 h2_t __attribute__((ext_vector_type(2)));

__device__ __forceinline__ unsigned int pk2(float a, float b) {
    return __builtin_bit_cast(unsigned int, __builtin_amdgcn_cvt_pkrtz(a, b));
}
__device__ __forceinline__ uint4 cvt8(float4 a, float4 b) {
    uint4 r;
    r.x = pk2(a.x, a.y); r.y = pk2(a.z, a.w);
    r.z = pk2(b.x, b.y); r.w = pk2(b.z, b.w);
    return r;
}
__device__ __forceinline__ float dot8(uint4 w, uint4 h, float acc) {
    acc = __builtin_amdgcn_fdot2(__builtin_bit_cast(h2_t, w.x), __builtin_bit_cast(h2_t, h.x), acc, false);
    acc = __builtin_amdgcn_fdot2(__builtin_bit_cast(h2_t, w.y), __builtin_bit_cast(h2_t, h.y), acc, false);
    acc = __builtin_amdgcn_fdot2(__builtin_bit_cast(h2_t, w.z), __builtin_bit_cast(h2_t, h.z), acc, false);
    acc = __builtin_amdgcn_fdot2(__builtin_bit_cast(h2_t, w.w), __builtin_bit_cast(h2_t, h.w), acc, false);
    return acc;
}
__device__ __forceinline__ float fast_sigmoid(float v) {
    return __builtin_amdgcn_rcpf(1.0f + __expf(-v));
}
__device__ __forceinline__ float fast_tanh(float v) {   // 2*sigmoid(2v)-1
    return fmaf(2.0f, __builtin_amdgcn_rcpf(1.0f + __expf(-2.0f * v)), -1.0f);
}

// Opaque register pin: a value defined by asm cannot be rematerialized from
// its original global load (R3/R4: LLVM sank the weight loads back into the
// loop -> ~30 TB/s of L2 re-reads every step, VGPR_Count stuck at 72).
#define PIN4(v) asm volatile("" : "+v"(v.x), "+v"(v.y), "+v"(v.z), "+v"(v.w))

// gate g, unit j, K-slice q: 24 f32 weights -> 3 uint4 (24 f16) = 12 VGPRs
#define WROW(g) \
    const float4* wp##g = reinterpret_cast<const float4*>(W_hh + ((g) * HID + j) * HID + q * 24); \
    uint4 w##g##_0 = cvt8(wp##g[0], wp##g[1]); \
    uint4 w##g##_1 = cvt8(wp##g[2], wp##g[3]); \
    uint4 w##g##_2 = cvt8(wp##g[4], wp##g[5]); \
    PIN4(w##g##_0); PIN4(w##g##_1); PIN4(w##g##_2);

#define DOT3(g, A) \
    A = dot8(w##g##_0, h0, A); A = dot8(w##g##_1, h1, A); A = dot8(w##g##_2, h2, A);

__global__ __launch_bounds__(448, 1)
void lstm_seq_kernel(const float* __restrict__ x,
                     const float* __restrict__ W_ih,
                     const float* __restrict__ W_hh,
                     const float* __restrict__ b_ih,
                     const float* __restrict__ b_hh,
                     const float* __restrict__ W_fc,
                     const float* __restrict__ b_fc,
                     float* __restrict__ out)
{
    const int b   = blockIdx.x;
    const int tid = threadIdx.x;   // 0..447: waves 0-5 = dot workers, wave 6 = FC

    // double-buffered hidden state, f16: [buf][12 x uint4] = 96 halves each
    __shared__ __align__(16) uint4 hq[2][12];

    if (tid < 24) ((uint4*)hq)[tid] = make_uint4(0u, 0u, 0u, 0u);
    __syncthreads();

    if (tid < 384) {
        // ---- worker: unit j = tid>>2 owns gates i,f,g,o over K-slice q = tid&3 (24 wide) ----
        const int j = tid >> 2;
        const int q = tid & 3;

        WROW(0) WROW(1) WROW(2) WROW(3)

        const float wih0 = W_ih[0 * HID + j], bs0 = b_ih[0 * HID + j] + b_hh[0 * HID + j];
        const float wih1 = W_ih[1 * HID + j], bs1 = b_ih[1 * HID + j] + b_hh[1 * HID + j];
        const float wih2 = W_ih[2 * HID + j], bs2 = b_ih[2 * HID + j] + b_hh[2 * HID + j];
        const float wih3 = W_ih[3 * HID + j], bs3 = b_ih[3 * HID + j] + b_hh[3 * HID + j];

        float c  = 0.0f;               // replicated across the quad (identical values)
        float xt = x[0 * BATCH + b];

        for (int t = 0; t < T_STEPS; ++t) {
            const int   tn    = (t + 1 < T_STEPS) ? (t + 1) : t;
            const float xnext = x[tn * BATCH + b];            // uniform prefetch

            // this thread's 24-half slice of h (broadcast within 16-lane groups, conflict-free)
            const uint4* hb = &hq[t & 1][q * 3];
            const uint4 h0 = hb[0], h1 = hb[1], h2 = hb[2];

            float ai = (q == 0) ? fmaf(xt, wih0, bs0) : 0.0f;
            float af = (q == 0) ? fmaf(xt, wih1, bs1) : 0.0f;
            float ag = (q == 0) ? fmaf(xt, wih2, bs2) : 0.0f;
            float ao = (q == 0) ? fmaf(xt, wih3, bs3) : 0.0f;
            DOT3(0, ai) DOT3(1, af) DOT3(2, ag) DOT3(3, ao)

            // quad reduce (xor1 + xor2 -> DPP): all 4 lanes get full 96-sums
            float si = ai + __shfl_xor(ai, 1); si += __shfl_xor(si, 2);
            float sf = af + __shfl_xor(af, 1); sf += __shfl_xor(sf, 2);
            float sg = ag + __shfl_xor(ag, 1); sg += __shfl_xor(sg, 2);
            float so = ao + __shfl_xor(ao, 1); so += __shfl_xor(so, 2);

            const float gi = fast_sigmoid(si);
            const float gf = fast_sigmoid(sf);
            const float gg = fast_tanh(sg);
            const float go = fast_sigmoid(so);
            c = fmaf(gf, c, gi * gg);
            const float hn = go * fast_tanh(c);

            if (q == 0) ((__fp16*)&hq[(t & 1) ^ 1][0])[j] = (__fp16)hn;
            __syncthreads();
            xt = xnext;
        }
    } else {
        // -------- FC wave: out[t-1] = h_t . W_fc + b_fc + x[t-1], one step deferred --------
        const int   lane = tid - 384;
        const float wfa  = W_fc[lane];
        const float wfb  = (lane < 32) ? W_fc[64 + lane] : 0.0f;
        const float bfc  = b_fc[0];

        float xfc = x[b];                                     // x[(t-1)] for t=1
        for (int t = 0; t < T_STEPS; ++t) {
            const float xnext = x[t * BATCH + b];             // becomes xfc for iter t+1
            if (t > 0) {
                const __fp16* hh = (const __fp16*)&hq[t & 1][0];   // h_t
                float s = (float)hh[lane] * wfa;
                if (lane < 32) s = fmaf((float)hh[64 + lane], wfb, s);
                #pragma unroll
                for (int d = 1; d < 64; d <<= 1) s += __shfl_xor(s, d);
                if (lane == 0) out[(t - 1) * BATCH + b] = s + bfc + xfc;
            }
            __syncthreads();
            xfc = xnext;
        }
        {   // final timestep: h_T is in hq[T&1] (T even -> buf 0)
            const __fp16* hh = (const __fp16*)&hq[T_STEPS & 1][0];
            float s = (float)hh[lane] * wfa;
            if (lane < 32) s = fmaf((float)hh[64 + lane], wfb, s);
            #pragma unroll
            for (int d = 1; d < 64; d <<= 1) s += __shfl_xor(s, d);
            if (lane == 0) out[(T_STEPS - 1) * BATCH + b] = s + bfc + xfc;
        }
    }
}

extern "C" void kernel_launch(void* const* d_in, const int* in_sizes, int n_in,
                              void* d_out, int out_size, void* d_ws, size_t ws_size,
                              hipStream_t stream) {
    (void)in_sizes; (void)n_in; (void)out_size; (void)d_ws; (void)ws_size;
    const float* x    = (const float*)d_in[0];
    const float* W_ih = (const float*)d_in[1];
    const float* W_hh = (const float*)d_in[2];
    const float* b_ih = (const float*)d_in[3];
    const float* b_hh = (const float*)d_in[4];
    const float* W_fc = (const float*)d_in[5];
    const float* b_fc = (const float*)d_in[6];
    float* out = (float*)d_out;

    lstm_seq_kernel<<<dim3(BATCH), dim3(448), 0, stream>>>(
        x, W_ih, W_hh, b_ih, b_hh, W_fc, b_fc, out);
}

// Round 7
// 5332.395 us; speedup vs baseline: 1.1493x; 1.1493x over previous
//
#include <hip/hip_runtime.h>

#define T_STEPS 8192
#define BATCH   128
#define HID     96

typedef __fp16 h2_t __attribute__((ext_vector_type(2)));

__device__ __forceinline__ unsigned int pk2(float a, float b) {
    return __builtin_bit_cast(unsigned int, __builtin_amdgcn_cvt_pkrtz(a, b));
}
__device__ __forceinline__ float dot8(uint4 w, uint4 h, float acc) {
    acc = __builtin_amdgcn_fdot2(__builtin_bit_cast(h2_t, w.x), __builtin_bit_cast(h2_t, h.x), acc, false);
    acc = __builtin_amdgcn_fdot2(__builtin_bit_cast(h2_t, w.y), __builtin_bit_cast(h2_t, h.y), acc, false);
    acc = __builtin_amdgcn_fdot2(__builtin_bit_cast(h2_t, w.z), __builtin_bit_cast(h2_t, h.z), acc, false);
    acc = __builtin_amdgcn_fdot2(__builtin_bit_cast(h2_t, w.w), __builtin_bit_cast(h2_t, h.w), acc, false);
    return acc;
}
__device__ __forceinline__ float fast_sigmoid(float v) {
    return __builtin_amdgcn_rcpf(1.0f + __expf(-v));
}
__device__ __forceinline__ float fast_tanh(float v) {   // 2*sigmoid(2v)-1
    return fmaf(2.0f, __builtin_amdgcn_rcpf(1.0f + __expf(-2.0f * v)), -1.0f);
}

// ---------------- prepack: W_hh (384x96 f32) -> f16 pairs (384x48 u32) in d_ws ----------------
// Removing the load->cvt chain from the main kernel is the point: R3/R5 showed LLVM
// rematerializes cvt_pkrtz chains into the loop (VGPR 72/36, ~30 TB/s L2 re-reads),
// while R1 proved PLAIN named vector loads stay register-resident (VGPR=124).
__global__ void prepack_kernel(const float* __restrict__ W_hh, unsigned int* __restrict__ wpk) {
    const int i = blockIdx.x * blockDim.x + threadIdx.x;   // over 384*48 packed words
    if (i < 4 * HID * (HID / 2)) {
        const int r = i / (HID / 2);
        const int k = i - r * (HID / 2);
        wpk[i] = pk2(W_hh[r * HID + 2 * k], W_hh[r * HID + 2 * k + 1]);
    }
}

// gate g: this thread's K-half = 6 plain uint4 loads (48 f16) -- named, no conversion
#define WROW(g) \
    const uint4* wq##g = ws_u4 + ((g) * HID + j) * 12 + p * 6; \
    const uint4 w##g##_0 = wq##g[0]; \
    const uint4 w##g##_1 = wq##g[1]; \
    const uint4 w##g##_2 = wq##g[2]; \
    const uint4 w##g##_3 = wq##g[3]; \
    const uint4 w##g##_4 = wq##g[4]; \
    const uint4 w##g##_5 = wq##g[5];

#define DOT6(g, A) \
    A = dot8(w##g##_0, h0, A); A = dot8(w##g##_1, h1, A); \
    A = dot8(w##g##_2, h2, A); A = dot8(w##g##_3, h3, A); \
    A = dot8(w##g##_4, h4, A); A = dot8(w##g##_5, h5, A);

__global__ __launch_bounds__(256, 1)
void lstm_seq_kernel(const float* __restrict__ x,
                     const float* __restrict__ W_ih,
                     const float* __restrict__ b_ih,
                     const float* __restrict__ b_hh,
                     const float* __restrict__ W_fc,
                     const float* __restrict__ b_fc,
                     const uint4* __restrict__ ws_u4,   // packed f16 W_hh
                     float* __restrict__ out)
{
    const int b   = blockIdx.x;
    const int tid = threadIdx.x;          // 0..255: waves 0-2 = dot workers, wave 3 = FC

    // double-buffered hidden state, f16: [buf][12 x uint4] = 96 halves each
    __shared__ __align__(16) uint4 hq[2][12];

    if (tid < 24) ((uint4*)hq)[tid] = make_uint4(0u, 0u, 0u, 0u);
    __syncthreads();

    if (tid < 192) {
        // -------- worker: unit j = tid>>1, K-half p = tid&1; owns gates i,f,g,o of j --------
        const int j = tid >> 1;
        const int p = tid & 1;

        WROW(0) WROW(1) WROW(2) WROW(3)

        const float wih0 = W_ih[0 * HID + j], bs0 = b_ih[0 * HID + j] + b_hh[0 * HID + j];
        const float wih1 = W_ih[1 * HID + j], bs1 = b_ih[1 * HID + j] + b_hh[1 * HID + j];
        const float wih2 = W_ih[2 * HID + j], bs2 = b_ih[2 * HID + j] + b_hh[2 * HID + j];
        const float wih3 = W_ih[3 * HID + j], bs3 = b_ih[3 * HID + j] + b_hh[3 * HID + j];

        float c  = 0.0f;                  // redundant across the lane pair (identical)
        float xt = x[0 * BATCH + b];

        for (int t = 0; t < T_STEPS; ++t) {
            const int   tn    = (t + 1 < T_STEPS) ? (t + 1) : t;
            const float xnext = x[tn * BATCH + b];            // uniform prefetch

            const uint4* hb = &hq[t & 1][p * 6];
            const uint4 h0 = hb[0], h1 = hb[1], h2 = hb[2];
            const uint4 h3 = hb[3], h4 = hb[4], h5 = hb[5];

            float ai = (p == 0) ? fmaf(xt, wih0, bs0) : 0.0f;
            float af = (p == 0) ? fmaf(xt, wih1, bs1) : 0.0f;
            float ag = (p == 0) ? fmaf(xt, wih2, bs2) : 0.0f;
            float ao = (p == 0) ? fmaf(xt, wih3, bs3) : 0.0f;
            DOT6(0, ai) DOT6(1, af) DOT6(2, ag) DOT6(3, ao)

            // join K-halves across the lane pair (xor-1 -> DPP quad_perm)
            const float si = ai + __shfl_xor(ai, 1);
            const float sf = af + __shfl_xor(af, 1);
            const float sg = ag + __shfl_xor(ag, 1);
            const float so = ao + __shfl_xor(ao, 1);

            const float gi = fast_sigmoid(si);
            const float gf = fast_sigmoid(sf);
            const float gg = fast_tanh(sg);
            const float go = fast_sigmoid(so);
            c = fmaf(gf, c, gi * gg);
            const float hn = go * fast_tanh(c);

            if (p == 0) ((__fp16*)&hq[(t & 1) ^ 1][0])[j] = (__fp16)hn;
            __syncthreads();
            xt = xnext;
        }
    } else {
        // -------- FC wave: out[t-1] = h_t . W_fc + b_fc + x[t-1], one step deferred --------
        const int   lane = tid - 192;
        const float wfa  = W_fc[lane];
        const float wfb  = (lane < 32) ? W_fc[64 + lane] : 0.0f;
        const float bfc  = b_fc[0];

        float xfc = x[b];                                     // x[(t-1)] for t=1
        for (int t = 0; t < T_STEPS; ++t) {
            const float xnext = x[t * BATCH + b];             // becomes xfc for iter t+1
            if (t > 0) {
                const __fp16* hh = (const __fp16*)&hq[t & 1][0];   // h_t
                float s = (float)hh[lane] * wfa;
                if (lane < 32) s = fmaf((float)hh[64 + lane], wfb, s);
                #pragma unroll
                for (int d = 1; d < 64; d <<= 1) s += __shfl_xor(s, d);
                if (lane == 0) out[(t - 1) * BATCH + b] = s + bfc + xfc;
            }
            __syncthreads();
            xfc = xnext;
        }
        {   // final timestep: h_T is in hq[T&1] (T even -> buf 0)
            const __fp16* hh = (const __fp16*)&hq[T_STEPS & 1][0];
            float s = (float)hh[lane] * wfa;
            if (lane < 32) s = fmaf((float)hh[64 + lane], wfb, s);
            #pragma unroll
            for (int d = 1; d < 64; d <<= 1) s += __shfl_xor(s, d);
            if (lane == 0) out[(T_STEPS - 1) * BATCH + b] = s + bfc + xfc;
        }
    }
}

extern "C" void kernel_launch(void* const* d_in, const int* in_sizes, int n_in,
                              void* d_out, int out_size, void* d_ws, size_t ws_size,
                              hipStream_t stream) {
    (void)in_sizes; (void)n_in; (void)out_size; (void)ws_size;
    const float* x    = (const float*)d_in[0];
    const float* W_ih = (const float*)d_in[1];
    const float* W_hh = (const float*)d_in[2];
    const float* b_ih = (const float*)d_in[3];
    const float* b_hh = (const float*)d_in[4];
    const float* W_fc = (const float*)d_in[5];
    const float* b_fc = (const float*)d_in[6];
    float* out = (float*)d_out;
    unsigned int* wpk = (unsigned int*)d_ws;       // 384*48 u32 = 73728 B

    const int npack = 4 * HID * (HID / 2);
    prepack_kernel<<<dim3((npack + 255) / 256), dim3(256), 0, stream>>>(W_hh, wpk);

    lstm_seq_kernel<<<dim3(BATCH), dim3(256), 0, stream>>>(
        x, W_ih, b_ih, b_hh, W_fc, b_fc, (const uint4*)wpk, out);
}